// Round 1
// 186.487 us; speedup vs baseline: 1.0066x; 1.0066x over previous
//
#include <hip/hip_runtime.h>
#include <hip/hip_bf16.h>

#define T_TOK 16384
#define DM 256
#define NE 8
#define HF 512
#define TM 64

typedef __bf16 bf16x8 __attribute__((ext_vector_type(8)));
typedef float f32x4 __attribute__((ext_vector_type(4)));

__device__ __forceinline__ unsigned short f2bf(float f) {
  unsigned u = __float_as_uint(f);
  u += 0x7fffu + ((u >> 16) & 1u);  // RNE (NaN not expected in this data)
  return (unsigned short)(u >> 16);
}

// Fast erf-based exact-form GELU. Abramowitz-Stegun 7.1.26, |abs err| < 1.5e-7,
// far below the bf16 rounding applied to h right after. ~17 VALU ops vs libm erff.
__device__ __forceinline__ float gelu_f(float v) {
  float s = fabsf(v) * 0.70710678118654752f;
  float t = __builtin_amdgcn_rcpf(1.0f + 0.3275911f * s);
  float p = t * (0.254829592f +
            t * (-0.284496736f +
            t * (1.421413741f +
            t * (-1.453152027f + t * 1.061405429f))));
  float e = 1.0f - p * __expf(-s * s);
  e = copysignf(e, v);
  return 0.5f * v * (1.0f + e);
}

// ---------------- gate: 4 threads/token fp64 split-D + shfl reduce -----------------
// grid 256 blocks (vs 64 before): 4x CU coverage, 4x fewer latency-exposed iterations.
__global__ __launch_bounds__(256) void gate_kernel(
    const float* __restrict__ x, const float* __restrict__ Wg,
    const float* __restrict__ bg, int* __restrict__ cnts, int* __restrict__ list) {
  __shared__ float wg_s[DM * NE];  // 8 KB
  __shared__ int hist[NE], base_s[NE], rank[NE];
  int tid = threadIdx.x;
#pragma unroll
  for (int i = 0; i < NE; i++) wg_s[tid * NE + i] = Wg[tid * NE + i];
  if (tid < NE) { hist[tid] = 0; rank[tid] = 0; }
  __syncthreads();

  int tl = tid >> 2;   // token within block, 0..63 (4-lane groups never straddle a wave)
  int cg = tid & 3;    // d-chunk 0..3, 64 floats each
  int t = blockIdx.x * 64 + tl;
  const float* xr = x + (size_t)t * DM + cg * 64;
  double acc[NE];
#pragma unroll
  for (int i = 0; i < NE; i++) acc[i] = 0.0;
  for (int d = 0; d < 64; d += 4) {
    float4 xv = *reinterpret_cast<const float4*>(xr + d);
    const float* w0 = &wg_s[(cg * 64 + d) * NE];
#pragma unroll
    for (int i = 0; i < NE; i++) {
      acc[i] += (double)xv.x * (double)w0[i] + (double)xv.y * (double)w0[NE + i] +
                (double)xv.z * (double)w0[2 * NE + i] + (double)xv.w * (double)w0[3 * NE + i];
    }
  }
#pragma unroll
  for (int i = 0; i < NE; i++) {  // butterfly: all 4 lanes end with the full sum
    acc[i] += __shfl_xor(acc[i], 1, 64);
    acc[i] += __shfl_xor(acc[i], 2, 64);
    acc[i] += (double)bg[i];
  }
  int e1 = 0;
#pragma unroll
  for (int i = 1; i < NE; i++) if (acc[i] > acc[e1]) e1 = i;  // ties -> lower index
  int e2 = -1;
#pragma unroll
  for (int i = 0; i < NE; i++) {
    if (i == e1) continue;
    if (e2 < 0 || acc[i] > acc[e2]) e2 = i;
  }

  if (cg == 0) {
    atomicAdd(&hist[e1], 1);
    atomicAdd(&hist[e2], 1);
  }
  __syncthreads();
  if (tid < NE) base_s[tid] = atomicAdd(&cnts[tid], hist[tid]);  // 8 global atomics/block
  __syncthreads();
  if (cg == 0) {
    int r1 = atomicAdd(&rank[e1], 1);
    list[e1 * T_TOK + base_s[e1] + r1] = t;
    int r2 = atomicAdd(&rank[e2], 1);
    list[e2 * T_TOK + base_s[e2] + r2] = t;
  }
}

// ---------------- transpose+cast: in fp32 [R][C] per slab -> out bf16 [C][R] ------
__global__ __launch_bounds__(256) void transpose_kernel(
    const float* __restrict__ in, unsigned short* __restrict__ out, int R, int C) {
  __shared__ float tile[32][33];
  int z = blockIdx.z;
  const float* src = in + (size_t)z * R * C;
  unsigned short* dst = out + (size_t)z * R * C;
  int c0 = blockIdx.x * 32, r0 = blockIdx.y * 32;
  int tx = threadIdx.x, ty = threadIdx.y;  // (32,8)
#pragma unroll
  for (int i = 0; i < 4; i++)
    tile[ty + i * 8][tx] = src[(size_t)(r0 + ty + i * 8) * C + c0 + tx];
  __syncthreads();
#pragma unroll
  for (int i = 0; i < 4; i++)
    dst[(size_t)(c0 + ty + i * 8) * R + r0 + tx] = f2bf(tile[tx][ty + i * 8]);
}

// ---------------- grouped FFN: 64-token tile, 8 waves, h-chunk=128, dbuf Hc -------
// w1t: [E][H][D] bf16 (k-contiguous for GEMM1 B-frags)
// w2t: [E][D][H] bf16 (k-contiguous for GEMM2 B-frags)
// LDS layout: XOR-swizzled (byte ^= (row&7)<<4), no padding -> conflict-free b128 reads.
__global__ __launch_bounds__(512, 4) void ffn_kernel(
    const float* __restrict__ x, const unsigned short* __restrict__ w1t,
    const float* __restrict__ b1, const unsigned short* __restrict__ w2t,
    const float* __restrict__ b2, const int* __restrict__ cnts,
    const int* __restrict__ list, float* __restrict__ out) {
  __shared__ unsigned short Xs[TM * DM];      // 32 KB, swizzled rows of 512 B
  __shared__ unsigned short Hc[2][TM * 128];  // 2 x 16 KB, swizzled rows of 256 B
  __shared__ int tok[TM];

  int e = blockIdx.x >> 8;
  int tile = blockIdx.x & 255;
  int cnt = cnts[e];
  int base = tile * TM;
  if (base >= cnt) return;
  int rowsv = min(TM, cnt - base);

  int tid = threadIdx.x;
  {  // stage X tile: fp32 -> bf16, gathered rows, 8 threads/row
    int r = tid >> 3, cg = tid & 7;
    int token = -1;
    if (r < rowsv) token = list[e * T_TOK + base + r];
    if (cg == 0) tok[r] = token;
    char* xrow = (char*)&Xs[r * DM];
    int swz = (r & 7) << 4;
    if (token >= 0) {
      const float* xr = x + (size_t)token * DM + cg * 32;
#pragma unroll
      for (int j = 0; j < 8; j++) {
        float4 v = *reinterpret_cast<const float4*>(xr + j * 4);
        unsigned long long pk = (unsigned long long)f2bf(v.x) |
                                ((unsigned long long)f2bf(v.y) << 16) |
                                ((unsigned long long)f2bf(v.z) << 32) |
                                ((unsigned long long)f2bf(v.w) << 48);
        *reinterpret_cast<unsigned long long*>(xrow + ((cg * 64 + j * 8) ^ swz)) = pk;
      }
    } else {
#pragma unroll
      for (int j = 0; j < 8; j++)
        *reinterpret_cast<unsigned long long*>(xrow + ((cg * 64 + j * 8) ^ swz)) = 0ull;
    }
  }
  __syncthreads();

  int w = tid >> 6, lane = tid & 63;   // 8 waves
  int quad = lane >> 4, l16 = lane & 15;
  int aswz = (l16 & 7) << 4;           // A-fragment row swizzle (row = mt*16 + l16)

  f32x4 zero4 = {0.f, 0.f, 0.f, 0.f};
  f32x4 oacc[4][2];
#pragma unroll
  for (int mt = 0; mt < 4; mt++)
#pragma unroll
    for (int nt = 0; nt < 2; nt++) oacc[mt][nt] = zero4;

  const unsigned short* w1e = w1t + (size_t)e * HF * DM;
  const unsigned short* w2e = w2t + (size_t)e * DM * HF;

  for (int hc = 0; hc < 4; ++hc) {
    // --- GEMM1: wave w computes h-cols [hc*128 + w*16, +16) over full K=256 ---
    int n0 = hc * 128 + w * 16;
    f32x4 pacc[4];
#pragma unroll
    for (int mt = 0; mt < 4; mt++) pacc[mt] = zero4;
    const unsigned short* bsrc = w1e + (size_t)(n0 + l16) * DM + quad * 8;
#pragma unroll
    for (int ks = 0; ks < 8; ++ks) {
      bf16x8 bfrag = *reinterpret_cast<const bf16x8*>(bsrc + ks * 32);
#pragma unroll
      for (int mt = 0; mt < 4; mt++) {
        const char* ab = (const char*)&Xs[(mt * 16 + l16) * DM];
        bf16x8 afrag = *reinterpret_cast<const bf16x8*>(ab + ((ks * 64 + quad * 16) ^ aswz));
        pacc[mt] = __builtin_amdgcn_mfma_f32_16x16x32_bf16(afrag, bfrag, pacc[mt], 0, 0, 0);
      }
    }
    float bias1 = b1[e * HF + n0 + l16];
    unsigned short* hbuf = &Hc[hc & 1][0];
#pragma unroll
    for (int mt = 0; mt < 4; mt++) {
#pragma unroll
      for (int r = 0; r < 4; r++) {
        int row = mt * 16 + quad * 4 + r;
        float g = gelu_f(pacc[mt][r] + bias1);
        char* hrow = (char*)&hbuf[row * 128];
        *reinterpret_cast<unsigned short*>(
            hrow + ((((w * 16 + l16) * 2)) ^ ((row & 7) << 4))) = f2bf(g);
      }
    }
    __syncthreads();  // only barrier per chunk: Hc[hc&1] complete; dbuf covers reuse
    // --- GEMM2 partial: oacc += Hc-chunk @ W2[k-chunk, wave's 32 d-cols] ---
#pragma unroll
    for (int ks2 = 0; ks2 < 4; ++ks2) {
      bf16x8 af[4];
#pragma unroll
      for (int mt = 0; mt < 4; mt++) {
        const char* hr = (const char*)&hbuf[(mt * 16 + l16) * 128];
        af[mt] = *reinterpret_cast<const bf16x8*>(hr + ((ks2 * 64 + quad * 16) ^ aswz));
      }
#pragma unroll
      for (int nt = 0; nt < 2; nt++) {
        int d = w * 32 + nt * 16 + l16;
        bf16x8 bfrag = *reinterpret_cast<const bf16x8*>(
            w2e + (size_t)d * HF + hc * 128 + ks2 * 32 + quad * 8);
#pragma unroll
        for (int mt = 0; mt < 4; mt++)
          oacc[mt][nt] =
              __builtin_amdgcn_mfma_f32_16x16x32_bf16(af[mt], bfrag, oacc[mt][nt], 0, 0, 0);
      }
    }
  }

  // --- epilogue: scatter-add contributions (+b2 per expert hit) ---
  float b2v[2];
#pragma unroll
  for (int nt = 0; nt < 2; nt++) b2v[nt] = b2[e * DM + w * 32 + nt * 16 + l16];
#pragma unroll
  for (int mt = 0; mt < 4; mt++) {
#pragma unroll
    for (int r = 0; r < 4; r++) {
      int m = mt * 16 + quad * 4 + r;
      int token = tok[m];
      if (token < 0) continue;
      float* orow = out + (size_t)token * DM;
#pragma unroll
      for (int nt = 0; nt < 2; nt++) {
        int d = w * 32 + nt * 16 + l16;
        atomicAdd(&orow[d], oacc[mt][nt][r] + b2v[nt]);
      }
    }
  }
}

extern "C" void kernel_launch(void* const* d_in, const int* in_sizes, int n_in,
                              void* d_out, int out_size, void* d_ws, size_t ws_size,
                              hipStream_t stream) {
  (void)in_sizes; (void)n_in; (void)ws_size;
  const float* x  = (const float*)d_in[0];
  const float* Wg = (const float*)d_in[1];
  const float* bg = (const float*)d_in[2];
  const float* W1 = (const float*)d_in[3];
  const float* b1 = (const float*)d_in[4];
  const float* W2 = (const float*)d_in[5];
  const float* b2 = (const float*)d_in[6];
  float* out = (float*)d_out;

  char* ws = (char*)d_ws;
  int* cnts = (int*)ws;                                      // 256 B (8 used)
  int* list = (int*)(ws + 256);                              // 8*16384*4 = 512 KB
  unsigned short* w1t = (unsigned short*)(ws + 256 + 524288);            // 2 MB
  unsigned short* w2t = (unsigned short*)(ws + 256 + 524288 + 2097152);  // 2 MB

  hipMemsetAsync(cnts, 0, 256, stream);
  hipMemsetAsync(d_out, 0, (size_t)out_size * sizeof(float), stream);

  dim3 tb(32, 8);
  // W1: per-expert [D=256][H=512] -> w1t [H][D]
  hipLaunchKernelGGL(transpose_kernel, dim3(HF / 32, DM / 32, NE), tb, 0, stream,
                     W1, w1t, DM, HF);
  // W2: per-expert [H=512][D=256] -> w2t [D][H]
  hipLaunchKernelGGL(transpose_kernel, dim3(DM / 32, HF / 32, NE), tb, 0, stream,
                     W2, w2t, HF, DM);
  hipLaunchKernelGGL(gate_kernel, dim3(T_TOK / 64), dim3(256), 0, stream,
                     x, Wg, bg, cnts, list);
  hipLaunchKernelGGL(ffn_kernel, dim3(NE * 256), dim3(512), 0, stream,
                     x, w1t, b1, w2t, b2, cnts, list, out);
}

// Round 2
// 160.556 us; speedup vs baseline: 1.1692x; 1.1615x over previous
//
#include <hip/hip_runtime.h>
#include <hip/hip_bf16.h>

#define T_TOK 16384
#define DM 256
#define NE 8
#define HF 512
#define TM 64
#define XS_LD 264  // 256 + 8 shorts pad: row stride 528 B -> granule walk, 2-way max
#define HC_LD 264

typedef __bf16 bf16x8 __attribute__((ext_vector_type(8)));
typedef float f32x4 __attribute__((ext_vector_type(4)));
typedef unsigned short u16x8 __attribute__((ext_vector_type(8)));

__device__ __forceinline__ unsigned short f2bf(float f) {
  unsigned u = __float_as_uint(f);
  u += 0x7fffu + ((u >> 16) & 1u);  // RNE (NaN not expected in this data)
  return (unsigned short)(u >> 16);
}

// Fast erf-based exact-form GELU (A&S 7.1.26, |err|<1.5e-7 << bf16 quantization).
__device__ __forceinline__ float gelu_f(float v) {
  float s = fabsf(v) * 0.70710678118654752f;
  float t = __builtin_amdgcn_rcpf(1.0f + 0.3275911f * s);
  float p = t * (0.254829592f +
            t * (-0.284496736f +
            t * (1.421413741f +
            t * (-1.453152027f + t * 1.061405429f))));
  float e = 1.0f - p * __expf(-s * s);
  e = copysignf(e, v);
  return 0.5f * v * (1.0f + e);
}

// ---------------- gate: 4 threads/token fp64 split-D + shfl reduce -----------------
__global__ __launch_bounds__(256) void gate_kernel(
    const float* __restrict__ x, const float* __restrict__ Wg,
    const float* __restrict__ bg, int* __restrict__ cnts, int* __restrict__ list) {
  __shared__ float wg_s[DM * NE];  // 8 KB
  __shared__ int hist[NE], base_s[NE], rank[NE];
  int tid = threadIdx.x;
#pragma unroll
  for (int i = 0; i < NE; i++) wg_s[tid * NE + i] = Wg[tid * NE + i];
  if (tid < NE) { hist[tid] = 0; rank[tid] = 0; }
  __syncthreads();

  int tl = tid >> 2;   // token within block (4-lane groups never straddle a wave)
  int cg = tid & 3;    // d-chunk 0..3, 64 floats each
  int t = blockIdx.x * 64 + tl;
  const float* xr = x + (size_t)t * DM + cg * 64;
  double acc[NE];
#pragma unroll
  for (int i = 0; i < NE; i++) acc[i] = 0.0;
  for (int d = 0; d < 64; d += 4) {
    float4 xv = *reinterpret_cast<const float4*>(xr + d);
    const float* w0 = &wg_s[(cg * 64 + d) * NE];
#pragma unroll
    for (int i = 0; i < NE; i++) {
      acc[i] += (double)xv.x * (double)w0[i] + (double)xv.y * (double)w0[NE + i] +
                (double)xv.z * (double)w0[2 * NE + i] + (double)xv.w * (double)w0[3 * NE + i];
    }
  }
#pragma unroll
  for (int i = 0; i < NE; i++) {
    acc[i] += __shfl_xor(acc[i], 1, 64);
    acc[i] += __shfl_xor(acc[i], 2, 64);
    acc[i] += (double)bg[i];
  }
  int e1 = 0;
#pragma unroll
  for (int i = 1; i < NE; i++) if (acc[i] > acc[e1]) e1 = i;  // ties -> lower index
  int e2 = -1;
#pragma unroll
  for (int i = 0; i < NE; i++) {
    if (i == e1) continue;
    if (e2 < 0 || acc[i] > acc[e2]) e2 = i;
  }

  if (cg == 0) {
    atomicAdd(&hist[e1], 1);
    atomicAdd(&hist[e2], 1);
  }
  __syncthreads();
  if (tid < NE) base_s[tid] = atomicAdd(&cnts[tid], hist[tid]);
  __syncthreads();
  if (cg == 0) {
    int r1 = atomicAdd(&rank[e1], 1);
    list[e1 * T_TOK + base_s[e1] + r1] = t;
    int r2 = atomicAdd(&rank[e2], 1);
    list[e2 * T_TOK + base_s[e2] + r2] = t;
  }
}

// ---------------- weight pack: in fp32 [E][K][N] -> lane-major MFMA B-fragment tiles
// Tile = 16 n-cols x 32 k. Packed elem index:
//   e*K*N + ((n>>4)*(K/32) + (k>>5))*512 + ((k>>3)&3)*128 + (n&15)*8 + (k&7)
// so a wave's B-frag load for (n0,k0) is base + lane*8 elements: one contiguous 1KB burst.
__global__ __launch_bounds__(256) void pack_kernel(
    const float* __restrict__ in, unsigned short* __restrict__ out, int K, int N) {
  int idx = blockIdx.x * 256 + threadIdx.x;
  int n = idx & (N - 1);
  int rest = idx / N;            // e*(K/8) + kq
  int kq = rest & ((K >> 3) - 1);
  int eidx = rest / (K >> 3);
  int k0 = kq * 8;
  const float* src = in + ((size_t)eidx * K + k0) * N + n;
  u16x8 pk;
#pragma unroll
  for (int j = 0; j < 8; j++) pk[j] = f2bf(src[(size_t)j * N]);
  size_t baseo = (size_t)eidx * K * N +
                 (size_t)((n >> 4) * (K >> 5) + (k0 >> 5)) * 512 +
                 (size_t)(((k0 >> 3) & 3) * 128 + (n & 15) * 8);
  *reinterpret_cast<u16x8*>(out + baseo) = pk;
}

// ---------------- grouped FFN: 64-token tile, 8 waves, 4x2 register tiling --------
// w1p: packed W1 (K=256=D, N=512=H); w2p: packed W2 (K=512=H, N=256=D).
// B-frag loads coalesced (lane*16B); A-frags from padded LDS, reused 2x over nt.
__global__ __launch_bounds__(512, 4) void ffn_kernel(
    const float* __restrict__ x, const unsigned short* __restrict__ w1p,
    const float* __restrict__ b1, const unsigned short* __restrict__ w2p,
    const float* __restrict__ b2, const int* __restrict__ cnts,
    const int* __restrict__ list, float* __restrict__ out) {
  __shared__ unsigned short Xs[TM * XS_LD];  // 33 KB
  __shared__ unsigned short Hc[TM * HC_LD];  // 33 KB (single buffer, 256-col chunks)
  __shared__ int tok[TM];

  int e = blockIdx.x >> 8;
  int tile = blockIdx.x & 255;
  int cnt = cnts[e];
  int base = tile * TM;
  if (base >= cnt) return;
  int rowsv = min(TM, cnt - base);

  int tid = threadIdx.x;
  {  // stage X tile: fp32 -> bf16, gathered rows, 8 threads/row
    int r = tid >> 3, cg = tid & 7;
    int token = -1;
    if (r < rowsv) token = list[e * T_TOK + base + r];
    if (cg == 0) tok[r] = token;
    unsigned short* xrow = &Xs[r * XS_LD + cg * 32];
    if (token >= 0) {
      const float* xr = x + (size_t)token * DM + cg * 32;
#pragma unroll
      for (int j = 0; j < 8; j++) {
        float4 v = *reinterpret_cast<const float4*>(xr + j * 4);
        unsigned long long pk = (unsigned long long)f2bf(v.x) |
                                ((unsigned long long)f2bf(v.y) << 16) |
                                ((unsigned long long)f2bf(v.z) << 32) |
                                ((unsigned long long)f2bf(v.w) << 48);
        *reinterpret_cast<unsigned long long*>(xrow + j * 4) = pk;
      }
    } else {
#pragma unroll
      for (int j = 0; j < 8; j++)
        *reinterpret_cast<unsigned long long*>(xrow + j * 4) = 0ull;
    }
  }
  __syncthreads();

  int w = tid >> 6, lane = tid & 63;
  int quad = lane >> 4, l16 = lane & 15;

  const unsigned short* w1e = w1p + (size_t)e * (HF * DM) + lane * 8;
  const unsigned short* w2e = w2p + (size_t)e * (DM * HF) + lane * 8;

  f32x4 zero4 = {0.f, 0.f, 0.f, 0.f};
  f32x4 oacc[4][2];
#pragma unroll
  for (int mt = 0; mt < 4; mt++)
#pragma unroll
    for (int nt = 0; nt < 2; nt++) oacc[mt][nt] = zero4;

  f32x4 pacc[4][2];

  // ================= chunk 0: GEMM1 (h cols w*32 .. w*32+32) ======================
#pragma unroll
  for (int mt = 0; mt < 4; mt++)
#pragma unroll
    for (int nt = 0; nt < 2; nt++) pacc[mt][nt] = zero4;
#pragma unroll
  for (int ks = 0; ks < 8; ks++) {
    bf16x8 a[4], bfr[2];
#pragma unroll
    for (int mt = 0; mt < 4; mt++)
      a[mt] = *reinterpret_cast<const bf16x8*>(&Xs[(mt * 16 + l16) * XS_LD + ks * 32 + quad * 8]);
#pragma unroll
    for (int nt = 0; nt < 2; nt++)
      bfr[nt] = *reinterpret_cast<const bf16x8*>(w1e + (size_t)(((w * 2 + nt) * 8 + ks)) * 512);
#pragma unroll
    for (int nt = 0; nt < 2; nt++)
#pragma unroll
      for (int mt = 0; mt < 4; mt++)
        pacc[mt][nt] = __builtin_amdgcn_mfma_f32_16x16x32_bf16(a[mt], bfr[nt], pacc[mt][nt], 0, 0, 0);
  }
#pragma unroll
  for (int nt = 0; nt < 2; nt++) {
    float bias1 = b1[e * HF + w * 32 + nt * 16 + l16];
#pragma unroll
    for (int mt = 0; mt < 4; mt++)
#pragma unroll
      for (int r = 0; r < 4; r++) {
        int row = mt * 16 + quad * 4 + r;
        Hc[row * HC_LD + w * 32 + nt * 16 + l16] = f2bf(gelu_f(pacc[mt][nt][r] + bias1));
      }
  }
  __syncthreads();  // Hc chunk 0 ready

  // ---- GEMM2 on chunk 0 (k = h 0..255), d cols w*32 .. +32 ----
#pragma unroll
  for (int ks2 = 0; ks2 < 8; ks2++) {
    bf16x8 a[4], bfr[2];
#pragma unroll
    for (int mt = 0; mt < 4; mt++)
      a[mt] = *reinterpret_cast<const bf16x8*>(&Hc[(mt * 16 + l16) * HC_LD + ks2 * 32 + quad * 8]);
#pragma unroll
    for (int nt = 0; nt < 2; nt++)
      bfr[nt] = *reinterpret_cast<const bf16x8*>(w2e + (size_t)((w * 2 + nt) * 16 + ks2) * 512);
#pragma unroll
    for (int nt = 0; nt < 2; nt++)
#pragma unroll
      for (int mt = 0; mt < 4; mt++)
        oacc[mt][nt] = __builtin_amdgcn_mfma_f32_16x16x32_bf16(a[mt], bfr[nt], oacc[mt][nt], 0, 0, 0);
  }

  // ---- GEMM1 chunk 1 compute (reads only Xs; overlaps GEMM2-c0 scheduling) ----
#pragma unroll
  for (int mt = 0; mt < 4; mt++)
#pragma unroll
    for (int nt = 0; nt < 2; nt++) pacc[mt][nt] = zero4;
#pragma unroll
  for (int ks = 0; ks < 8; ks++) {
    bf16x8 a[4], bfr[2];
#pragma unroll
    for (int mt = 0; mt < 4; mt++)
      a[mt] = *reinterpret_cast<const bf16x8*>(&Xs[(mt * 16 + l16) * XS_LD + ks * 32 + quad * 8]);
#pragma unroll
    for (int nt = 0; nt < 2; nt++)
      bfr[nt] = *reinterpret_cast<const bf16x8*>(w1e + (size_t)((16 + w * 2 + nt) * 8 + ks) * 512);
#pragma unroll
    for (int nt = 0; nt < 2; nt++)
#pragma unroll
      for (int mt = 0; mt < 4; mt++)
        pacc[mt][nt] = __builtin_amdgcn_mfma_f32_16x16x32_bf16(a[mt], bfr[nt], pacc[mt][nt], 0, 0, 0);
  }
  __syncthreads();  // all GEMM2-c0 reads of Hc done -> safe to overwrite

#pragma unroll
  for (int nt = 0; nt < 2; nt++) {
    float bias1 = b1[e * HF + 256 + w * 32 + nt * 16 + l16];
#pragma unroll
    for (int mt = 0; mt < 4; mt++)
#pragma unroll
      for (int r = 0; r < 4; r++) {
        int row = mt * 16 + quad * 4 + r;
        Hc[row * HC_LD + w * 32 + nt * 16 + l16] = f2bf(gelu_f(pacc[mt][nt][r] + bias1));
      }
  }
  __syncthreads();  // Hc chunk 1 ready

  // ---- GEMM2 on chunk 1 (k = h 256..511) ----
#pragma unroll
  for (int ks2 = 0; ks2 < 8; ks2++) {
    bf16x8 a[4], bfr[2];
#pragma unroll
    for (int mt = 0; mt < 4; mt++)
      a[mt] = *reinterpret_cast<const bf16x8*>(&Hc[(mt * 16 + l16) * HC_LD + ks2 * 32 + quad * 8]);
#pragma unroll
    for (int nt = 0; nt < 2; nt++)
      bfr[nt] = *reinterpret_cast<const bf16x8*>(w2e + (size_t)((w * 2 + nt) * 16 + 8 + ks2) * 512);
#pragma unroll
    for (int nt = 0; nt < 2; nt++)
#pragma unroll
      for (int mt = 0; mt < 4; mt++)
        oacc[mt][nt] = __builtin_amdgcn_mfma_f32_16x16x32_bf16(a[mt], bfr[nt], oacc[mt][nt], 0, 0, 0);
  }

  // --- epilogue: scatter-add contributions (+b2 per expert hit) ---
  float b2v[2];
#pragma unroll
  for (int nt = 0; nt < 2; nt++) b2v[nt] = b2[e * DM + w * 32 + nt * 16 + l16];
#pragma unroll
  for (int mt = 0; mt < 4; mt++) {
#pragma unroll
    for (int r = 0; r < 4; r++) {
      int m = mt * 16 + quad * 4 + r;
      int token = tok[m];
      if (token < 0) continue;
      float* orow = out + (size_t)token * DM;
#pragma unroll
      for (int nt = 0; nt < 2; nt++) {
        int d = w * 32 + nt * 16 + l16;
        atomicAdd(&orow[d], oacc[mt][nt][r] + b2v[nt]);
      }
    }
  }
}

extern "C" void kernel_launch(void* const* d_in, const int* in_sizes, int n_in,
                              void* d_out, int out_size, void* d_ws, size_t ws_size,
                              hipStream_t stream) {
  (void)in_sizes; (void)n_in; (void)ws_size;
  const float* x  = (const float*)d_in[0];
  const float* Wg = (const float*)d_in[1];
  const float* bg = (const float*)d_in[2];
  const float* W1 = (const float*)d_in[3];
  const float* b1 = (const float*)d_in[4];
  const float* W2 = (const float*)d_in[5];
  const float* b2 = (const float*)d_in[6];
  float* out = (float*)d_out;

  char* ws = (char*)d_ws;
  int* cnts = (int*)ws;                                      // 256 B (8 used)
  int* list = (int*)(ws + 256);                              // 8*16384*4 = 512 KB
  unsigned short* w1p = (unsigned short*)(ws + 256 + 524288);            // 2 MB
  unsigned short* w2p = (unsigned short*)(ws + 256 + 524288 + 2097152);  // 2 MB

  hipMemsetAsync(cnts, 0, 256, stream);
  hipMemsetAsync(d_out, 0, (size_t)out_size * sizeof(float), stream);

  // W1 is [E][D][H] = [e][k][n] (K=256,N=512); W2 is [E][H][D] = [e][k][n] (K=512,N=256).
  // Both pack directly -- no transpose needed.
  hipLaunchKernelGGL(pack_kernel, dim3(NE * DM * HF / 8 / 256), dim3(256), 0, stream,
                     W1, w1p, DM, HF);
  hipLaunchKernelGGL(pack_kernel, dim3(NE * DM * HF / 8 / 256), dim3(256), 0, stream,
                     W2, w2p, HF, DM);
  hipLaunchKernelGGL(gate_kernel, dim3(T_TOK / 64), dim3(256), 0, stream,
                     x, Wg, bg, cnts, list);
  hipLaunchKernelGGL(ffn_kernel, dim3(NE * 256), dim3(512), 0, stream,
                     x, w1p, b1, w2p, b2, cnts, list, out);
}

// Round 3
// 152.793 us; speedup vs baseline: 1.2286x; 1.0508x over previous
//
#include <hip/hip_runtime.h>
#include <hip/hip_bf16.h>

#define T_TOK 16384
#define DM 256
#define NE 8
#define HF 512
#define TM 64
#define XS_LD 264  // 256 + 8 shorts pad: row stride 528 B, ~2-way max on b128 reads

typedef __bf16 bf16x8 __attribute__((ext_vector_type(8)));
typedef float f32x4 __attribute__((ext_vector_type(4)));
typedef unsigned short u16x8 __attribute__((ext_vector_type(8)));

#define MFMA16(a, b, c) __builtin_amdgcn_mfma_f32_16x16x32_bf16((a), (b), (c), 0, 0, 0)

__device__ __forceinline__ unsigned short f2bf(float f) {
  unsigned u = __float_as_uint(f);
  u += 0x7fffu + ((u >> 16) & 1u);  // RNE (NaN not expected in this data)
  return (unsigned short)(u >> 16);
}

// Fast erf-based exact-form GELU (A&S 7.1.26, |err|<1.5e-7 << bf16 quantization).
__device__ __forceinline__ float gelu_f(float v) {
  float s = fabsf(v) * 0.70710678118654752f;
  float t = __builtin_amdgcn_rcpf(1.0f + 0.3275911f * s);
  float p = t * (0.254829592f +
            t * (-0.284496736f +
            t * (1.421413741f +
            t * (-1.453152027f + t * 1.061405429f))));
  float e = 1.0f - p * __expf(-s * s);
  e = copysignf(e, v);
  return 0.5f * v * (1.0f + e);
}

// ---- pack: fp32 [E][K][N] -> lane-major MFMA B-fragment tiles (16n x 32k) --------
// elem index: e*K*N + ((n>>4)*(K/32) + (k>>5))*512 + ((k>>3)&3)*128 + (n&15)*8 + (k&7)
// -> wave B-frag load = base + lane*8 elems: one contiguous 1KB burst.
__device__ __forceinline__ void pack_body(const float* __restrict__ in,
                                          unsigned short* __restrict__ out,
                                          int K, int N, int idx) {
  int n = idx & (N - 1);
  int rest = idx / N;
  int kq = rest & ((K >> 3) - 1);
  int eidx = rest / (K >> 3);
  int k0 = kq * 8;
  const float* src = in + ((size_t)eidx * K + k0) * N + n;
  u16x8 pk;
#pragma unroll
  for (int j = 0; j < 8; j++) pk[j] = f2bf(src[(size_t)j * N]);
  size_t baseo = (size_t)eidx * K * N +
                 (size_t)((n >> 4) * (K >> 5) + (k0 >> 5)) * 512 +
                 (size_t)(((k0 >> 3) & 3) * 128 + (n & 15) * 8);
  *reinterpret_cast<u16x8*>(out + baseo) = pk;
}

// ---- prep: pack W1 (512 blocks) + pack W2 (512 blocks) + gate (256 blocks) -------
__global__ __launch_bounds__(256) void prep_kernel(
    const float* __restrict__ W1, const float* __restrict__ W2,
    unsigned short* __restrict__ w1p, unsigned short* __restrict__ w2p,
    const float* __restrict__ x, const float* __restrict__ Wg,
    const float* __restrict__ bg, int* __restrict__ cnts, int* __restrict__ list) {
  __shared__ float wg_s[DM * NE];  // 8 KB (gate path only)
  __shared__ int hist[NE], base_s[NE], rank[NE];
  int b = blockIdx.x;
  int tid = threadIdx.x;
  if (b < 512) {
    pack_body(W1, w1p, DM, HF, b * 256 + tid);
    return;
  }
  if (b < 1024) {
    pack_body(W2, w2p, HF, DM, (b - 512) * 256 + tid);
    return;
  }
  // ---- gate: 4 threads/token fp64 split-D + shfl reduce ----
  int gb = b - 1024;
#pragma unroll
  for (int i = 0; i < NE; i++) wg_s[tid * NE + i] = Wg[tid * NE + i];
  if (tid < NE) { hist[tid] = 0; rank[tid] = 0; }
  __syncthreads();

  int tl = tid >> 2;   // token within block (4-lane groups never straddle a wave)
  int cg = tid & 3;    // d-chunk 0..3, 64 floats each
  int t = gb * 64 + tl;
  const float* xr = x + (size_t)t * DM + cg * 64;
  double acc[NE];
#pragma unroll
  for (int i = 0; i < NE; i++) acc[i] = 0.0;
  for (int d = 0; d < 64; d += 4) {
    float4 xv = *reinterpret_cast<const float4*>(xr + d);
    const float* w0 = &wg_s[(cg * 64 + d) * NE];
#pragma unroll
    for (int i = 0; i < NE; i++) {
      acc[i] += (double)xv.x * (double)w0[i] + (double)xv.y * (double)w0[NE + i] +
                (double)xv.z * (double)w0[2 * NE + i] + (double)xv.w * (double)w0[3 * NE + i];
    }
  }
#pragma unroll
  for (int i = 0; i < NE; i++) {
    acc[i] += __shfl_xor(acc[i], 1, 64);
    acc[i] += __shfl_xor(acc[i], 2, 64);
    acc[i] += (double)bg[i];
  }
  int e1 = 0;
#pragma unroll
  for (int i = 1; i < NE; i++) if (acc[i] > acc[e1]) e1 = i;  // ties -> lower index
  int e2 = -1;
#pragma unroll
  for (int i = 0; i < NE; i++) {
    if (i == e1) continue;
    if (e2 < 0 || acc[i] > acc[e2]) e2 = i;
  }
  if (cg == 0) {
    atomicAdd(&hist[e1], 1);
    atomicAdd(&hist[e2], 1);
  }
  __syncthreads();
  if (tid < NE) base_s[tid] = atomicAdd(&cnts[tid], hist[tid]);
  __syncthreads();
  if (cg == 0) {
    int r1 = atomicAdd(&rank[e1], 1);
    list[e1 * T_TOK + base_s[e1] + r1] = t;
    int r2 = atomicAdd(&rank[e2], 1);
    list[e2 * T_TOK + base_s[e2] + r2] = t;
  }
}

// ---------------- grouped FFN: 64-token tile, 8 waves, 4x2 register tiling --------
// Restructured: GEMM1 over all 512 h-cols first (Hc-lo in Hl, Hc-hi reuses Xs),
// then GEMM2 over all 512 k. pacc/oacc never both live -> VGPR headroom spent on a
// 1-deep B-fragment register prefetch chain that crosses all phase boundaries.
__global__ __launch_bounds__(512, 4) void ffn_kernel(
    const float* __restrict__ x, const unsigned short* __restrict__ w1p,
    const float* __restrict__ b1, const unsigned short* __restrict__ w2p,
    const float* __restrict__ b2, const int* __restrict__ cnts,
    const int* __restrict__ list, float* __restrict__ out) {
  __shared__ unsigned short Xs[TM * XS_LD];  // 33KB: X tile, later Hc cols 256..511
  __shared__ unsigned short Hl[TM * XS_LD];  // 33KB: Hc cols 0..255
  __shared__ int tok[TM];

  int e = blockIdx.x >> 8;
  int tile = blockIdx.x & 255;
  int cnt = cnts[e];
  int base = tile * TM;
  if (base >= cnt) return;
  int rowsv = min(TM, cnt - base);

  int tid = threadIdx.x;
  int w = tid >> 6, lane = tid & 63;
  int quad = lane >> 4, l16 = lane & 15;

  const unsigned short* w1e = w1p + (size_t)e * (HF * DM) + lane * 8;
  const unsigned short* w2e = w2p + (size_t)e * (DM * HF) + lane * 8;

  // early-issue first GEMM1 B-frags: independent of staging, hides L2 latency
  bf16x8 bcur0 = *reinterpret_cast<const bf16x8*>(w1e + (size_t)((w * 2 + 0) * 8) * 512);
  bf16x8 bcur1 = *reinterpret_cast<const bf16x8*>(w1e + (size_t)((w * 2 + 1) * 8) * 512);

  {  // stage X tile: fp32 -> bf16, gathered rows, 8 threads/row
    int r = tid >> 3, cg = tid & 7;
    int token = -1;
    if (r < rowsv) token = list[e * T_TOK + base + r];
    if (cg == 0) tok[r] = token;
    unsigned short* xrow = &Xs[r * XS_LD + cg * 32];
    if (token >= 0) {
      const float* xr = x + (size_t)token * DM + cg * 32;
#pragma unroll
      for (int j = 0; j < 8; j++) {
        float4 v = *reinterpret_cast<const float4*>(xr + j * 4);
        unsigned long long pk = (unsigned long long)f2bf(v.x) |
                                ((unsigned long long)f2bf(v.y) << 16) |
                                ((unsigned long long)f2bf(v.z) << 32) |
                                ((unsigned long long)f2bf(v.w) << 48);
        *reinterpret_cast<unsigned long long*>(xrow + j * 4) = pk;
      }
    } else {
#pragma unroll
      for (int j = 0; j < 8; j++)
        *reinterpret_cast<unsigned long long*>(xrow + j * 4) = 0ull;
    }
  }
  __syncthreads();

  f32x4 zero4 = {0.f, 0.f, 0.f, 0.f};
  f32x4 pacc[4][2];

  // ================= GEMM1 chunk 0: h-cols w*32 .. +32 ===========================
#pragma unroll
  for (int mt = 0; mt < 4; mt++)
#pragma unroll
    for (int nt = 0; nt < 2; nt++) pacc[mt][nt] = zero4;
#pragma unroll
  for (int ks = 0; ks < 8; ks++) {
    bf16x8 bn0, bn1;
    if (ks < 7) {  // prefetch next k-tile
      bn0 = *reinterpret_cast<const bf16x8*>(w1e + (size_t)((w * 2 + 0) * 8 + ks + 1) * 512);
      bn1 = *reinterpret_cast<const bf16x8*>(w1e + (size_t)((w * 2 + 1) * 8 + ks + 1) * 512);
    } else {       // prefetch chunk-1 first k-tile
      bn0 = *reinterpret_cast<const bf16x8*>(w1e + (size_t)((16 + w * 2 + 0) * 8) * 512);
      bn1 = *reinterpret_cast<const bf16x8*>(w1e + (size_t)((16 + w * 2 + 1) * 8) * 512);
    }
    bf16x8 a[4];
#pragma unroll
    for (int mt = 0; mt < 4; mt++)
      a[mt] = *reinterpret_cast<const bf16x8*>(&Xs[(mt * 16 + l16) * XS_LD + ks * 32 + quad * 8]);
#pragma unroll
    for (int mt = 0; mt < 4; mt++) {
      pacc[mt][0] = MFMA16(a[mt], bcur0, pacc[mt][0]);
      pacc[mt][1] = MFMA16(a[mt], bcur1, pacc[mt][1]);
    }
    bcur0 = bn0; bcur1 = bn1;
  }
  // gelu + write Hc-lo (separate region, no barrier needed before writes)
#pragma unroll
  for (int nt = 0; nt < 2; nt++) {
    float bias1 = b1[e * HF + w * 32 + nt * 16 + l16];
#pragma unroll
    for (int mt = 0; mt < 4; mt++)
#pragma unroll
      for (int r = 0; r < 4; r++) {
        int row = mt * 16 + quad * 4 + r;
        Hl[row * XS_LD + w * 32 + nt * 16 + l16] = f2bf(gelu_f(pacc[mt][nt][r] + bias1));
      }
  }

  // ================= GEMM1 chunk 1: h-cols 256 + w*32 .. +32 =====================
#pragma unroll
  for (int mt = 0; mt < 4; mt++)
#pragma unroll
    for (int nt = 0; nt < 2; nt++) pacc[mt][nt] = zero4;
#pragma unroll
  for (int ks = 0; ks < 8; ks++) {
    bf16x8 bn0, bn1;
    if (ks < 7) {
      bn0 = *reinterpret_cast<const bf16x8*>(w1e + (size_t)((16 + w * 2 + 0) * 8 + ks + 1) * 512);
      bn1 = *reinterpret_cast<const bf16x8*>(w1e + (size_t)((16 + w * 2 + 1) * 8 + ks + 1) * 512);
    } else {       // prefetch first GEMM2 W2 k-tile: issued BEFORE both barriers
      bn0 = *reinterpret_cast<const bf16x8*>(w2e + (size_t)((w * 2 + 0) * 16) * 512);
      bn1 = *reinterpret_cast<const bf16x8*>(w2e + (size_t)((w * 2 + 1) * 16) * 512);
    }
    bf16x8 a[4];
#pragma unroll
    for (int mt = 0; mt < 4; mt++)
      a[mt] = *reinterpret_cast<const bf16x8*>(&Xs[(mt * 16 + l16) * XS_LD + ks * 32 + quad * 8]);
#pragma unroll
    for (int mt = 0; mt < 4; mt++) {
      pacc[mt][0] = MFMA16(a[mt], bcur0, pacc[mt][0]);
      pacc[mt][1] = MFMA16(a[mt], bcur1, pacc[mt][1]);
    }
    bcur0 = bn0; bcur1 = bn1;
  }
  __syncthreads();  // all waves done reading Xs -> safe to overwrite with Hc-hi
#pragma unroll
  for (int nt = 0; nt < 2; nt++) {
    float bias1 = b1[e * HF + 256 + w * 32 + nt * 16 + l16];
#pragma unroll
    for (int mt = 0; mt < 4; mt++)
#pragma unroll
      for (int r = 0; r < 4; r++) {
        int row = mt * 16 + quad * 4 + r;
        Xs[row * XS_LD + w * 32 + nt * 16 + l16] = f2bf(gelu_f(pacc[mt][nt][r] + bias1));
      }
  }
  __syncthreads();  // Hc fully ready (lo in Hl, hi in Xs)

  // ================= GEMM2: d-cols w*32 .. +32, k = 0..511 =======================
  f32x4 oacc[4][2];
#pragma unroll
  for (int mt = 0; mt < 4; mt++)
#pragma unroll
    for (int nt = 0; nt < 2; nt++) oacc[mt][nt] = zero4;
#pragma unroll
  for (int ks2 = 0; ks2 < 16; ks2++) {
    bf16x8 bn0, bn1;
    if (ks2 < 15) {
      bn0 = *reinterpret_cast<const bf16x8*>(w2e + (size_t)((w * 2 + 0) * 16 + ks2 + 1) * 512);
      bn1 = *reinterpret_cast<const bf16x8*>(w2e + (size_t)((w * 2 + 1) * 16 + ks2 + 1) * 512);
    }
    const unsigned short* hbase = (ks2 < 8) ? Hl : Xs;
    int col = (ks2 & 7) * 32 + quad * 8;
    bf16x8 a[4];
#pragma unroll
    for (int mt = 0; mt < 4; mt++)
      a[mt] = *reinterpret_cast<const bf16x8*>(&hbase[(mt * 16 + l16) * XS_LD + col]);
#pragma unroll
    for (int mt = 0; mt < 4; mt++) {
      oacc[mt][0] = MFMA16(a[mt], bcur0, oacc[mt][0]);
      oacc[mt][1] = MFMA16(a[mt], bcur1, oacc[mt][1]);
    }
    if (ks2 < 15) { bcur0 = bn0; bcur1 = bn1; }
  }

  // --- epilogue: scatter-add contributions (+b2 per expert hit) ---
  float b2v[2];
#pragma unroll
  for (int nt = 0; nt < 2; nt++) b2v[nt] = b2[e * DM + w * 32 + nt * 16 + l16];
#pragma unroll
  for (int mt = 0; mt < 4; mt++) {
#pragma unroll
    for (int r = 0; r < 4; r++) {
      int m = mt * 16 + quad * 4 + r;
      int token = tok[m];
      if (token < 0) continue;
      float* orow = out + (size_t)token * DM;
#pragma unroll
      for (int nt = 0; nt < 2; nt++) {
        int d = w * 32 + nt * 16 + l16;
        atomicAdd(&orow[d], oacc[mt][nt][r] + b2v[nt]);
      }
    }
  }
}

extern "C" void kernel_launch(void* const* d_in, const int* in_sizes, int n_in,
                              void* d_out, int out_size, void* d_ws, size_t ws_size,
                              hipStream_t stream) {
  (void)in_sizes; (void)n_in; (void)ws_size;
  const float* x  = (const float*)d_in[0];
  const float* Wg = (const float*)d_in[1];
  const float* bg = (const float*)d_in[2];
  const float* W1 = (const float*)d_in[3];
  const float* b1 = (const float*)d_in[4];
  const float* W2 = (const float*)d_in[5];
  const float* b2 = (const float*)d_in[6];
  float* out = (float*)d_out;

  char* ws = (char*)d_ws;
  int* cnts = (int*)ws;                                      // 256 B (8 used)
  int* list = (int*)(ws + 256);                              // 8*16384*4 = 512 KB
  unsigned short* w1p = (unsigned short*)(ws + 256 + 524288);            // 2 MB
  unsigned short* w2p = (unsigned short*)(ws + 256 + 524288 + 2097152);  // 2 MB

  hipMemsetAsync(cnts, 0, 256, stream);
  hipMemsetAsync(d_out, 0, (size_t)out_size * sizeof(float), stream);

  // prep: blocks [0,512) pack W1, [512,1024) pack W2, [1024,1280) gate.
  // W1 is [E][D][H] = [e][k][n] (K=256,N=512); W2 is [E][H][D] (K=512,N=256).
  hipLaunchKernelGGL(prep_kernel, dim3(1280), dim3(256), 0, stream,
                     W1, W2, w1p, w2p, x, Wg, bg, cnts, list);
  hipLaunchKernelGGL(ffn_kernel, dim3(NE * 256), dim3(512), 0, stream,
                     x, w1p, b1, w2p, b2, cnts, list, out);
}

// Round 4
// 151.740 us; speedup vs baseline: 1.2371x; 1.0069x over previous
//
#include <hip/hip_runtime.h>
#include <hip/hip_bf16.h>

#define T_TOK 16384
#define DM 256
#define NE 8
#define HF 512
#define TM 64
#define XS_LD 264  // 256 + 8 shorts pad: row stride 528 B, ~2-way max on b128 reads

typedef __bf16 bf16x8 __attribute__((ext_vector_type(8)));
typedef float f32x4 __attribute__((ext_vector_type(4)));
typedef unsigned short u16x8 __attribute__((ext_vector_type(8)));

#define MFMA16(a, b, c) __builtin_amdgcn_mfma_f32_16x16x32_bf16((a), (b), (c), 0, 0, 0)

__device__ __forceinline__ unsigned short f2bf(float f) {
  unsigned u = __float_as_uint(f);
  u += 0x7fffu + ((u >> 16) & 1u);  // RNE (NaN not expected in this data)
  return (unsigned short)(u >> 16);
}

// Fast erf-based exact-form GELU (A&S 7.1.26, |err|<1.5e-7 << bf16 quantization).
__device__ __forceinline__ float gelu_f(float v) {
  float s = fabsf(v) * 0.70710678118654752f;
  float t = __builtin_amdgcn_rcpf(1.0f + 0.3275911f * s);
  float p = t * (0.254829592f +
            t * (-0.284496736f +
            t * (1.421413741f +
            t * (-1.453152027f + t * 1.061405429f))));
  float e = 1.0f - p * __expf(-s * s);
  e = copysignf(e, v);
  return 0.5f * v * (1.0f + e);
}

// ---- pack: fp32 [E][K][N] -> lane-major MFMA B-fragment tiles (16n x 32k) --------
// elem index: e*K*N + ((n>>4)*(K/32) + (k>>5))*512 + ((k>>3)&3)*128 + (n&15)*8 + (k&7)
// -> wave B-frag load = base + lane*8 elems: one contiguous 1KB burst.
__device__ __forceinline__ void pack_body(const float* __restrict__ in,
                                          unsigned short* __restrict__ out,
                                          int K, int N, int idx) {
  int n = idx & (N - 1);
  int rest = idx / N;
  int kq = rest & ((K >> 3) - 1);
  int eidx = rest / (K >> 3);
  int k0 = kq * 8;
  const float* src = in + ((size_t)eidx * K + k0) * N + n;
  u16x8 pk;
#pragma unroll
  for (int j = 0; j < 8; j++) pk[j] = f2bf(src[(size_t)j * N]);
  size_t baseo = (size_t)eidx * K * N +
                 (size_t)((n >> 4) * (K >> 5) + (k0 >> 5)) * 512 +
                 (size_t)(((k0 >> 3) & 3) * 128 + (n & 15) * 8);
  *reinterpret_cast<u16x8*>(out + baseo) = pk;
}

// ---- prep: pack W1 (512 blocks) + pack W2 (512 blocks) + gate (256 blocks) -------
__global__ __launch_bounds__(256) void prep_kernel(
    const float* __restrict__ W1, const float* __restrict__ W2,
    unsigned short* __restrict__ w1p, unsigned short* __restrict__ w2p,
    const float* __restrict__ x, const float* __restrict__ Wg,
    const float* __restrict__ bg, int* __restrict__ cnts, int* __restrict__ list) {
  __shared__ float wg_s[DM * NE];  // 8 KB (gate path only)
  __shared__ int hist[NE], base_s[NE], rank[NE];
  int b = blockIdx.x;
  int tid = threadIdx.x;
  if (b < 512) {
    pack_body(W1, w1p, DM, HF, b * 256 + tid);
    return;
  }
  if (b < 1024) {
    pack_body(W2, w2p, HF, DM, (b - 512) * 256 + tid);
    return;
  }
  // ---- gate: 4 threads/token fp64 split-D + shfl reduce ----
  int gb = b - 1024;
  {  // vectorized Wg stage: 2x float4 per thread
    float4 wv0 = *reinterpret_cast<const float4*>(Wg + tid * 8);
    float4 wv1 = *reinterpret_cast<const float4*>(Wg + tid * 8 + 4);
    *reinterpret_cast<float4*>(&wg_s[tid * 8]) = wv0;
    *reinterpret_cast<float4*>(&wg_s[tid * 8 + 4]) = wv1;
  }
  if (tid < NE) { hist[tid] = 0; rank[tid] = 0; }
  __syncthreads();

  int tl = tid >> 2;   // token within block (4-lane groups never straddle a wave)
  int cg = tid & 3;    // d-chunk 0..3, 64 floats each
  int t = gb * 64 + tl;
  const float* xr = x + (size_t)t * DM + cg * 64;
  double acc[NE];
#pragma unroll
  for (int i = 0; i < NE; i++) acc[i] = 0.0;
  for (int d = 0; d < 64; d += 4) {
    float4 xv = *reinterpret_cast<const float4*>(xr + d);
    const float* w0 = &wg_s[(cg * 64 + d) * NE];
    float xa[4] = {xv.x, xv.y, xv.z, xv.w};
#pragma unroll
    for (int dd = 0; dd < 4; dd++) {  // 2x ds_read_b128 per d-row (was 8x b32)
      float4 wa = *reinterpret_cast<const float4*>(w0 + dd * NE);
      float4 wb = *reinterpret_cast<const float4*>(w0 + dd * NE + 4);
      double xd = (double)xa[dd];
      acc[0] += xd * (double)wa.x; acc[1] += xd * (double)wa.y;
      acc[2] += xd * (double)wa.z; acc[3] += xd * (double)wa.w;
      acc[4] += xd * (double)wb.x; acc[5] += xd * (double)wb.y;
      acc[6] += xd * (double)wb.z; acc[7] += xd * (double)wb.w;
    }
  }
#pragma unroll
  for (int i = 0; i < NE; i++) {
    acc[i] += __shfl_xor(acc[i], 1, 64);
    acc[i] += __shfl_xor(acc[i], 2, 64);
    acc[i] += (double)bg[i];
  }
  int e1 = 0;
#pragma unroll
  for (int i = 1; i < NE; i++) if (acc[i] > acc[e1]) e1 = i;  // ties -> lower index
  int e2 = -1;
#pragma unroll
  for (int i = 0; i < NE; i++) {
    if (i == e1) continue;
    if (e2 < 0 || acc[i] > acc[e2]) e2 = i;
  }
  if (cg == 0) {
    atomicAdd(&hist[e1], 1);
    atomicAdd(&hist[e2], 1);
  }
  __syncthreads();
  if (tid < NE) base_s[tid] = atomicAdd(&cnts[tid], hist[tid]);
  __syncthreads();
  if (cg == 0) {
    int r1 = atomicAdd(&rank[e1], 1);
    list[e1 * T_TOK + base_s[e1] + r1] = t;
    int r2 = atomicAdd(&rank[e2], 1);
    list[e2 * T_TOK + base_s[e2] + r2] = t;
  }
}

// ---------------- grouped FFN: 64-token tile, 8 waves, 4x2 register tiling --------
// XCD-aware mapping: e = blockIdx & 7 -> all blocks of expert e land on XCD e
// (blockIdx round-robins XCDs), so each XCD's 4MB L2 holds exactly its one
// expert's 512KB packed weights -> B-frag loads are L2 hits instead of L2 thrash.
__global__ __launch_bounds__(512, 4) void ffn_kernel(
    const float* __restrict__ x, const unsigned short* __restrict__ w1p,
    const float* __restrict__ b1, const unsigned short* __restrict__ w2p,
    const float* __restrict__ b2, const int* __restrict__ cnts,
    const int* __restrict__ list, float* __restrict__ out) {
  __shared__ unsigned short Xs[TM * XS_LD];  // 33KB: X tile, later Hc cols 256..511
  __shared__ unsigned short Hl[TM * XS_LD];  // 33KB: Hc cols 0..255
  __shared__ int tok[TM];

  int e = blockIdx.x & 7;
  int tile = blockIdx.x >> 3;
  int cnt = cnts[e];
  int base = tile * TM;
  if (base >= cnt) return;
  int rowsv = min(TM, cnt - base);

  int tid = threadIdx.x;
  int w = tid >> 6, lane = tid & 63;
  int quad = lane >> 4, l16 = lane & 15;

  const unsigned short* w1e = w1p + (size_t)e * (HF * DM) + lane * 8;
  const unsigned short* w2e = w2p + (size_t)e * (DM * HF) + lane * 8;

  // early-issue first GEMM1 B-frags: independent of staging, hides L2 latency
  bf16x8 bcur0 = *reinterpret_cast<const bf16x8*>(w1e + (size_t)((w * 2 + 0) * 8) * 512);
  bf16x8 bcur1 = *reinterpret_cast<const bf16x8*>(w1e + (size_t)((w * 2 + 1) * 8) * 512);

  {  // stage X tile: fp32 -> bf16, gathered rows, 8 threads/row
    int r = tid >> 3, cg = tid & 7;
    int token = -1;
    if (r < rowsv) token = list[e * T_TOK + base + r];
    if (cg == 0) tok[r] = token;
    unsigned short* xrow = &Xs[r * XS_LD + cg * 32];
    if (token >= 0) {
      const float* xr = x + (size_t)token * DM + cg * 32;
#pragma unroll
      for (int j = 0; j < 8; j++) {
        float4 v = *reinterpret_cast<const float4*>(xr + j * 4);
        unsigned long long pk = (unsigned long long)f2bf(v.x) |
                                ((unsigned long long)f2bf(v.y) << 16) |
                                ((unsigned long long)f2bf(v.z) << 32) |
                                ((unsigned long long)f2bf(v.w) << 48);
        *reinterpret_cast<unsigned long long*>(xrow + j * 4) = pk;
      }
    } else {
#pragma unroll
      for (int j = 0; j < 8; j++)
        *reinterpret_cast<unsigned long long*>(xrow + j * 4) = 0ull;
    }
  }
  __syncthreads();

  f32x4 zero4 = {0.f, 0.f, 0.f, 0.f};
  f32x4 pacc[4][2];

  // ================= GEMM1 chunk 0: h-cols w*32 .. +32 ===========================
#pragma unroll
  for (int mt = 0; mt < 4; mt++)
#pragma unroll
    for (int nt = 0; nt < 2; nt++) pacc[mt][nt] = zero4;
#pragma unroll
  for (int ks = 0; ks < 8; ks++) {
    bf16x8 bn0, bn1;
    if (ks < 7) {  // prefetch next k-tile
      bn0 = *reinterpret_cast<const bf16x8*>(w1e + (size_t)((w * 2 + 0) * 8 + ks + 1) * 512);
      bn1 = *reinterpret_cast<const bf16x8*>(w1e + (size_t)((w * 2 + 1) * 8 + ks + 1) * 512);
    } else {       // prefetch chunk-1 first k-tile
      bn0 = *reinterpret_cast<const bf16x8*>(w1e + (size_t)((16 + w * 2 + 0) * 8) * 512);
      bn1 = *reinterpret_cast<const bf16x8*>(w1e + (size_t)((16 + w * 2 + 1) * 8) * 512);
    }
    bf16x8 a[4];
#pragma unroll
    for (int mt = 0; mt < 4; mt++)
      a[mt] = *reinterpret_cast<const bf16x8*>(&Xs[(mt * 16 + l16) * XS_LD + ks * 32 + quad * 8]);
#pragma unroll
    for (int mt = 0; mt < 4; mt++) {
      pacc[mt][0] = MFMA16(a[mt], bcur0, pacc[mt][0]);
      pacc[mt][1] = MFMA16(a[mt], bcur1, pacc[mt][1]);
    }
    bcur0 = bn0; bcur1 = bn1;
  }
  // gelu + write Hc-lo (separate region, no barrier needed before writes)
#pragma unroll
  for (int nt = 0; nt < 2; nt++) {
    float bias1 = b1[e * HF + w * 32 + nt * 16 + l16];
#pragma unroll
    for (int mt = 0; mt < 4; mt++)
#pragma unroll
      for (int r = 0; r < 4; r++) {
        int row = mt * 16 + quad * 4 + r;
        Hl[row * XS_LD + w * 32 + nt * 16 + l16] = f2bf(gelu_f(pacc[mt][nt][r] + bias1));
      }
  }

  // ================= GEMM1 chunk 1: h-cols 256 + w*32 .. +32 =====================
#pragma unroll
  for (int mt = 0; mt < 4; mt++)
#pragma unroll
    for (int nt = 0; nt < 2; nt++) pacc[mt][nt] = zero4;
#pragma unroll
  for (int ks = 0; ks < 8; ks++) {
    bf16x8 bn0, bn1;
    if (ks < 7) {
      bn0 = *reinterpret_cast<const bf16x8*>(w1e + (size_t)((16 + w * 2 + 0) * 8 + ks + 1) * 512);
      bn1 = *reinterpret_cast<const bf16x8*>(w1e + (size_t)((16 + w * 2 + 1) * 8 + ks + 1) * 512);
    } else {       // prefetch first GEMM2 W2 k-tile: issued BEFORE both barriers
      bn0 = *reinterpret_cast<const bf16x8*>(w2e + (size_t)((w * 2 + 0) * 16) * 512);
      bn1 = *reinterpret_cast<const bf16x8*>(w2e + (size_t)((w * 2 + 1) * 16) * 512);
    }
    bf16x8 a[4];
#pragma unroll
    for (int mt = 0; mt < 4; mt++)
      a[mt] = *reinterpret_cast<const bf16x8*>(&Xs[(mt * 16 + l16) * XS_LD + ks * 32 + quad * 8]);
#pragma unroll
    for (int mt = 0; mt < 4; mt++) {
      pacc[mt][0] = MFMA16(a[mt], bcur0, pacc[mt][0]);
      pacc[mt][1] = MFMA16(a[mt], bcur1, pacc[mt][1]);
    }
    bcur0 = bn0; bcur1 = bn1;
  }
  __syncthreads();  // all waves done reading Xs -> safe to overwrite with Hc-hi
#pragma unroll
  for (int nt = 0; nt < 2; nt++) {
    float bias1 = b1[e * HF + 256 + w * 32 + nt * 16 + l16];
#pragma unroll
    for (int mt = 0; mt < 4; mt++)
#pragma unroll
      for (int r = 0; r < 4; r++) {
        int row = mt * 16 + quad * 4 + r;
        Xs[row * XS_LD + w * 32 + nt * 16 + l16] = f2bf(gelu_f(pacc[mt][nt][r] + bias1));
      }
  }
  __syncthreads();  // Hc fully ready (lo in Hl, hi in Xs)

  // ================= GEMM2: d-cols w*32 .. +32, k = 0..511 =======================
  f32x4 oacc[4][2];
#pragma unroll
  for (int mt = 0; mt < 4; mt++)
#pragma unroll
    for (int nt = 0; nt < 2; nt++) oacc[mt][nt] = zero4;
#pragma unroll
  for (int ks2 = 0; ks2 < 16; ks2++) {
    bf16x8 bn0, bn1;
    if (ks2 < 15) {
      bn0 = *reinterpret_cast<const bf16x8*>(w2e + (size_t)((w * 2 + 0) * 16 + ks2 + 1) * 512);
      bn1 = *reinterpret_cast<const bf16x8*>(w2e + (size_t)((w * 2 + 1) * 16 + ks2 + 1) * 512);
    }
    const unsigned short* hbase = (ks2 < 8) ? Hl : Xs;
    int col = (ks2 & 7) * 32 + quad * 8;
    bf16x8 a[4];
#pragma unroll
    for (int mt = 0; mt < 4; mt++)
      a[mt] = *reinterpret_cast<const bf16x8*>(&hbase[(mt * 16 + l16) * XS_LD + col]);
#pragma unroll
    for (int mt = 0; mt < 4; mt++) {
      oacc[mt][0] = MFMA16(a[mt], bcur0, oacc[mt][0]);
      oacc[mt][1] = MFMA16(a[mt], bcur1, oacc[mt][1]);
    }
    if (ks2 < 15) { bcur0 = bn0; bcur1 = bn1; }
  }

  // --- epilogue: scatter-add contributions (+b2 per expert hit) ---
  float b2v[2];
#pragma unroll
  for (int nt = 0; nt < 2; nt++) b2v[nt] = b2[e * DM + w * 32 + nt * 16 + l16];
#pragma unroll
  for (int mt = 0; mt < 4; mt++) {
#pragma unroll
    for (int r = 0; r < 4; r++) {
      int m = mt * 16 + quad * 4 + r;
      int token = tok[m];
      if (token < 0) continue;
      float* orow = out + (size_t)token * DM;
#pragma unroll
      for (int nt = 0; nt < 2; nt++) {
        int d = w * 32 + nt * 16 + l16;
        atomicAdd(&orow[d], oacc[mt][nt][r] + b2v[nt]);
      }
    }
  }
}

extern "C" void kernel_launch(void* const* d_in, const int* in_sizes, int n_in,
                              void* d_out, int out_size, void* d_ws, size_t ws_size,
                              hipStream_t stream) {
  (void)in_sizes; (void)n_in; (void)ws_size;
  const float* x  = (const float*)d_in[0];
  const float* Wg = (const float*)d_in[1];
  const float* bg = (const float*)d_in[2];
  const float* W1 = (const float*)d_in[3];
  const float* b1 = (const float*)d_in[4];
  const float* W2 = (const float*)d_in[5];
  const float* b2 = (const float*)d_in[6];
  float* out = (float*)d_out;

  char* ws = (char*)d_ws;
  int* cnts = (int*)ws;                                      // 256 B (8 used)
  int* list = (int*)(ws + 256);                              // 8*16384*4 = 512 KB
  unsigned short* w1p = (unsigned short*)(ws + 256 + 524288);            // 2 MB
  unsigned short* w2p = (unsigned short*)(ws + 256 + 524288 + 2097152);  // 2 MB

  hipMemsetAsync(cnts, 0, 256, stream);
  hipMemsetAsync(d_out, 0, (size_t)out_size * sizeof(float), stream);

  // prep: blocks [0,512) pack W1, [512,1024) pack W2, [1024,1280) gate.
  // W1 is [E][D][H] = [e][k][n] (K=256,N=512); W2 is [E][H][D] (K=512,N=256).
  hipLaunchKernelGGL(prep_kernel, dim3(1280), dim3(256), 0, stream,
                     W1, W2, w1p, w2p, x, Wg, bg, cnts, list);
  hipLaunchKernelGGL(ffn_kernel, dim3(NE * 256), dim3(512), 0, stream,
                     x, w1p, b1, w2p, b2, cnts, list, out);
}

// Round 7
// 146.270 us; speedup vs baseline: 1.2834x; 1.0374x over previous
//
#include <hip/hip_runtime.h>
#include <hip/hip_bf16.h>

#define T_TOK 16384
#define DM 256
#define NE 8
#define HF 512
#define TM 32
#define XS_LD 264  // 256 + 8 shorts pad: row stride 528 B, ~2-way max on b128 reads

typedef __bf16 bf16x8 __attribute__((ext_vector_type(8)));
typedef float f32x4 __attribute__((ext_vector_type(4)));
typedef unsigned short u16x8 __attribute__((ext_vector_type(8)));

#define MFMA16(a, b, c) __builtin_amdgcn_mfma_f32_16x16x32_bf16((a), (b), (c), 0, 0, 0)

__device__ __forceinline__ unsigned short f2bf(float f) {
  unsigned u = __float_as_uint(f);
  u += 0x7fffu + ((u >> 16) & 1u);  // RNE (NaN not expected in this data)
  return (unsigned short)(u >> 16);
}

// Fast erf-based exact-form GELU (A&S 7.1.26, |err|<1.5e-7 << bf16 quantization).
__device__ __forceinline__ float gelu_f(float v) {
  float s = fabsf(v) * 0.70710678118654752f;
  float t = __builtin_amdgcn_rcpf(1.0f + 0.3275911f * s);
  float p = t * (0.254829592f +
            t * (-0.284496736f +
            t * (1.421413741f +
            t * (-1.453152027f + t * 1.061405429f))));
  float e = 1.0f - p * __expf(-s * s);
  e = copysignf(e, v);
  return 0.5f * v * (1.0f + e);
}

// ---- pack: fp32 [E][K][N] -> lane-major MFMA B-fragment tiles (16n x 32k) --------
// elem index: e*K*N + ((n>>4)*(K/32) + (k>>5))*512 + ((k>>3)&3)*128 + (n&15)*8 + (k&7)
__device__ __forceinline__ void pack_body(const float* __restrict__ in,
                                          unsigned short* __restrict__ out,
                                          int K, int N, int idx) {
  int n = idx & (N - 1);
  int rest = idx / N;
  int kq = rest & ((K >> 3) - 1);
  int eidx = rest / (K >> 3);
  int k0 = kq * 8;
  const float* src = in + ((size_t)eidx * K + k0) * N + n;
  u16x8 pk;
#pragma unroll
  for (int j = 0; j < 8; j++) pk[j] = f2bf(src[(size_t)j * N]);
  size_t baseo = (size_t)eidx * K * N +
                 (size_t)((n >> 4) * (K >> 5) + (k0 >> 5)) * 512 +
                 (size_t)(((k0 >> 3) & 3) * 128 + (n & 15) * 8);
  *reinterpret_cast<u16x8*>(out + baseo) = pk;
}

// ---- prep: pack W1 (512 blocks) + pack W2 (512 blocks) + gate (256 blocks) -------
// (verbatim round-4 verified version)
__global__ __launch_bounds__(256) void prep_kernel(
    const float* __restrict__ W1, const float* __restrict__ W2,
    unsigned short* __restrict__ w1p, unsigned short* __restrict__ w2p,
    const float* __restrict__ x, const float* __restrict__ Wg,
    const float* __restrict__ bg, int* __restrict__ cnts, int* __restrict__ list) {
  __shared__ float wg_s[DM * NE];  // 8 KB (gate path only)
  __shared__ int hist[NE], base_s[NE], rank[NE];
  int b = blockIdx.x;
  int tid = threadIdx.x;
  if (b < 512) {
    pack_body(W1, w1p, DM, HF, b * 256 + tid);
    return;
  }
  if (b < 1024) {
    pack_body(W2, w2p, HF, DM, (b - 512) * 256 + tid);
    return;
  }
  // ---- gate: 4 threads/token fp64 split-D + shfl reduce ----
  int gb = b - 1024;
  {  // vectorized Wg stage: 2x float4 per thread
    float4 wv0 = *reinterpret_cast<const float4*>(Wg + tid * 8);
    float4 wv1 = *reinterpret_cast<const float4*>(Wg + tid * 8 + 4);
    *reinterpret_cast<float4*>(&wg_s[tid * 8]) = wv0;
    *reinterpret_cast<float4*>(&wg_s[tid * 8 + 4]) = wv1;
  }
  if (tid < NE) { hist[tid] = 0; rank[tid] = 0; }
  __syncthreads();

  int tl = tid >> 2;   // token within block (4-lane groups never straddle a wave)
  int cg = tid & 3;    // d-chunk 0..3, 64 floats each
  int t = gb * 64 + tl;
  const float* xr = x + (size_t)t * DM + cg * 64;
  double acc[NE];
#pragma unroll
  for (int i = 0; i < NE; i++) acc[i] = 0.0;
  for (int d = 0; d < 64; d += 4) {
    float4 xv = *reinterpret_cast<const float4*>(xr + d);
    const float* w0 = &wg_s[(cg * 64 + d) * NE];
    float xa[4] = {xv.x, xv.y, xv.z, xv.w};
#pragma unroll
    for (int dd = 0; dd < 4; dd++) {  // 2x ds_read_b128 per d-row
      float4 wa = *reinterpret_cast<const float4*>(w0 + dd * NE);
      float4 wb = *reinterpret_cast<const float4*>(w0 + dd * NE + 4);
      double xd = (double)xa[dd];
      acc[0] += xd * (double)wa.x; acc[1] += xd * (double)wa.y;
      acc[2] += xd * (double)wa.z; acc[3] += xd * (double)wa.w;
      acc[4] += xd * (double)wb.x; acc[5] += xd * (double)wb.y;
      acc[6] += xd * (double)wb.z; acc[7] += xd * (double)wb.w;
    }
  }
#pragma unroll
  for (int i = 0; i < NE; i++) {
    acc[i] += __shfl_xor(acc[i], 1, 64);
    acc[i] += __shfl_xor(acc[i], 2, 64);
    acc[i] += (double)bg[i];
  }
  int e1 = 0;
#pragma unroll
  for (int i = 1; i < NE; i++) if (acc[i] > acc[e1]) e1 = i;  // ties -> lower index
  int e2 = -1;
#pragma unroll
  for (int i = 0; i < NE; i++) {
    if (i == e1) continue;
    if (e2 < 0 || acc[i] > acc[e2]) e2 = i;
  }
  if (cg == 0) {
    atomicAdd(&hist[e1], 1);
    atomicAdd(&hist[e2], 1);
  }
  __syncthreads();
  if (tid < NE) base_s[tid] = atomicAdd(&cnts[tid], hist[tid]);
  __syncthreads();
  if (cg == 0) {
    int r1 = atomicAdd(&rank[e1], 1);
    list[e1 * T_TOK + base_s[e1] + r1] = t;
    int r2 = atomicAdd(&rank[e2], 1);
    list[e2 * T_TOK + base_s[e2] + r2] = t;
  }
}

// ---------------- grouped FFN: 32-token tile, 4 waves, 2x4 register tiling --------
// Occupancy probe: TM 64->32, block 512->256 threads. LDS 34KB + ~92 regs ->
// 4 blocks/CU (vs 2), giving 4 independent phase streams per CU to overlap the
// stage->GEMM1->gelu->GEMM2->atomics serial chain. Per-wave MFMA structure,
// coalesced packed B-frags, 1-deep prefetch chain, XCD binding all preserved.
__global__ __launch_bounds__(256, 4) void ffn_kernel(
    const float* __restrict__ x, const unsigned short* __restrict__ w1p,
    const float* __restrict__ b1, const unsigned short* __restrict__ w2p,
    const float* __restrict__ b2, const int* __restrict__ cnts,
    const int* __restrict__ list, float* __restrict__ out) {
  __shared__ unsigned short Xs[TM * XS_LD];  // 16.9KB: X tile, later Hc cols 256..511
  __shared__ unsigned short Hl[TM * XS_LD];  // 16.9KB: Hc cols 0..255
  __shared__ int tok[TM];

  int e = blockIdx.x & 7;     // expert <-> XCD binding
  int tile = blockIdx.x >> 3;
  int cnt = cnts[e];
  int base = tile * TM;
  if (base >= cnt) return;
  int rowsv = min(TM, cnt - base);

  int tid = threadIdx.x;
  int w = tid >> 6, lane = tid & 63;   // 4 waves
  int quad = lane >> 4, l16 = lane & 15;

  const unsigned short* w1e = w1p + (size_t)e * (HF * DM) + lane * 8;
  const unsigned short* w2e = w2p + (size_t)e * (DM * HF) + lane * 8;

  // early-issue first GEMM1 B-frags (independent of staging)
  bf16x8 bcur[4];
#pragma unroll
  for (int nt = 0; nt < 4; nt++)
    bcur[nt] = *reinterpret_cast<const bf16x8*>(w1e + (size_t)((w * 4 + nt) * 8) * 512);

  {  // stage X tile: fp32 -> bf16, gathered rows, 8 threads/row
    int r = tid >> 3, cg = tid & 7;
    int token = -1;
    if (r < rowsv) token = list[e * T_TOK + base + r];
    if (cg == 0) tok[r] = token;
    unsigned short* xrow = &Xs[r * XS_LD + cg * 32];
    if (token >= 0) {
      const float* xr = x + (size_t)token * DM + cg * 32;
#pragma unroll
      for (int j = 0; j < 8; j++) {
        float4 v = *reinterpret_cast<const float4*>(xr + j * 4);
        unsigned long long pk = (unsigned long long)f2bf(v.x) |
                                ((unsigned long long)f2bf(v.y) << 16) |
                                ((unsigned long long)f2bf(v.z) << 32) |
                                ((unsigned long long)f2bf(v.w) << 48);
        *reinterpret_cast<unsigned long long*>(xrow + j * 4) = pk;
      }
    } else {
#pragma unroll
      for (int j = 0; j < 8; j++)
        *reinterpret_cast<unsigned long long*>(xrow + j * 4) = 0ull;
    }
  }
  __syncthreads();

  f32x4 zero4 = {0.f, 0.f, 0.f, 0.f};
  f32x4 pacc[2][4];

  // ===== GEMM1 chunk 0: h-cols w*64 .. +64 (4 n-tiles) =====
#pragma unroll
  for (int mt = 0; mt < 2; mt++)
#pragma unroll
    for (int nt = 0; nt < 4; nt++) pacc[mt][nt] = zero4;
#pragma unroll
  for (int ks = 0; ks < 8; ks++) {
    bf16x8 bn[4];
#pragma unroll
    for (int nt = 0; nt < 4; nt++) {
      int tn = (ks < 7) ? (w * 4 + nt) : (16 + w * 4 + nt);
      int kk = (ks < 7) ? (ks + 1) : 0;
      bn[nt] = *reinterpret_cast<const bf16x8*>(w1e + (size_t)(tn * 8 + kk) * 512);
    }
    bf16x8 a[2];
#pragma unroll
    for (int mt = 0; mt < 2; mt++)
      a[mt] = *reinterpret_cast<const bf16x8*>(&Xs[(mt * 16 + l16) * XS_LD + ks * 32 + quad * 8]);
#pragma unroll
    for (int nt = 0; nt < 4; nt++)
#pragma unroll
      for (int mt = 0; mt < 2; mt++)
        pacc[mt][nt] = MFMA16(a[mt], bcur[nt], pacc[mt][nt]);
#pragma unroll
    for (int nt = 0; nt < 4; nt++) bcur[nt] = bn[nt];
  }
  // gelu + write Hc-lo (separate region, no barrier needed before writes)
#pragma unroll
  for (int nt = 0; nt < 4; nt++) {
    float bias1 = b1[e * HF + w * 64 + nt * 16 + l16];
#pragma unroll
    for (int mt = 0; mt < 2; mt++)
#pragma unroll
      for (int r = 0; r < 4; r++) {
        int row = mt * 16 + quad * 4 + r;
        Hl[row * XS_LD + w * 64 + nt * 16 + l16] = f2bf(gelu_f(pacc[mt][nt][r] + bias1));
      }
  }

  // ===== GEMM1 chunk 1: h-cols 256 + w*64 .. +64 =====
#pragma unroll
  for (int mt = 0; mt < 2; mt++)
#pragma unroll
    for (int nt = 0; nt < 4; nt++) pacc[mt][nt] = zero4;
#pragma unroll
  for (int ks = 0; ks < 8; ks++) {
    bf16x8 bn[4];
#pragma unroll
    for (int nt = 0; nt < 4; nt++) {
      if (ks < 7) {
        bn[nt] = *reinterpret_cast<const bf16x8*>(
            w1e + (size_t)((16 + w * 4 + nt) * 8 + ks + 1) * 512);
      } else {  // prefetch first GEMM2 W2 k-tile before both barriers
        bn[nt] = *reinterpret_cast<const bf16x8*>(w2e + (size_t)((w * 4 + nt) * 16) * 512);
      }
    }
    bf16x8 a[2];
#pragma unroll
    for (int mt = 0; mt < 2; mt++)
      a[mt] = *reinterpret_cast<const bf16x8*>(&Xs[(mt * 16 + l16) * XS_LD + ks * 32 + quad * 8]);
#pragma unroll
    for (int nt = 0; nt < 4; nt++)
#pragma unroll
      for (int mt = 0; mt < 2; mt++)
        pacc[mt][nt] = MFMA16(a[mt], bcur[nt], pacc[mt][nt]);
#pragma unroll
    for (int nt = 0; nt < 4; nt++) bcur[nt] = bn[nt];
  }
  __syncthreads();  // all waves done reading Xs -> safe to overwrite with Hc-hi
#pragma unroll
  for (int nt = 0; nt < 4; nt++) {
    float bias1 = b1[e * HF + 256 + w * 64 + nt * 16 + l16];
#pragma unroll
    for (int mt = 0; mt < 2; mt++)
#pragma unroll
      for (int r = 0; r < 4; r++) {
        int row = mt * 16 + quad * 4 + r;
        Xs[row * XS_LD + w * 64 + nt * 16 + l16] = f2bf(gelu_f(pacc[mt][nt][r] + bias1));
      }
  }
  __syncthreads();  // Hc fully ready (lo in Hl, hi in Xs)

  // ===== GEMM2: d-cols w*64 .. +64, k = 0..511 =====
  f32x4 oacc[2][4];
#pragma unroll
  for (int mt = 0; mt < 2; mt++)
#pragma unroll
    for (int nt = 0; nt < 4; nt++) oacc[mt][nt] = zero4;
#pragma unroll
  for (int ks2 = 0; ks2 < 16; ks2++) {
    bf16x8 bn[4];
    if (ks2 < 15) {
#pragma unroll
      for (int nt = 0; nt < 4; nt++)
        bn[nt] = *reinterpret_cast<const bf16x8*>(
            w2e + (size_t)((w * 4 + nt) * 16 + ks2 + 1) * 512);
    }
    const unsigned short* hbase = (ks2 < 8) ? Hl : Xs;
    int col = (ks2 & 7) * 32 + quad * 8;
    bf16x8 a[2];
#pragma unroll
    for (int mt = 0; mt < 2; mt++)
      a[mt] = *reinterpret_cast<const bf16x8*>(&hbase[(mt * 16 + l16) * XS_LD + col]);
#pragma unroll
    for (int nt = 0; nt < 4; nt++)
#pragma unroll
      for (int mt = 0; mt < 2; mt++)
        oacc[mt][nt] = MFMA16(a[mt], bcur[nt], oacc[mt][nt]);
    if (ks2 < 15) {
#pragma unroll
      for (int nt = 0; nt < 4; nt++) bcur[nt] = bn[nt];
    }
  }

  // ===== epilogue: scatter-add (+b2 per expert hit) =====
  float b2v[4];
#pragma unroll
  for (int nt = 0; nt < 4; nt++) b2v[nt] = b2[e * DM + w * 64 + nt * 16 + l16];
#pragma unroll
  for (int mt = 0; mt < 2; mt++) {
#pragma unroll
    for (int r = 0; r < 4; r++) {
      int m = mt * 16 + quad * 4 + r;
      int token = tok[m];
      if (token < 0) continue;
      float* orow = out + (size_t)token * DM;
#pragma unroll
      for (int nt = 0; nt < 4; nt++) {
        int d = w * 64 + nt * 16 + l16;
        atomicAdd(&orow[d], oacc[mt][nt][r] + b2v[nt]);
      }
    }
  }
}

extern "C" void kernel_launch(void* const* d_in, const int* in_sizes, int n_in,
                              void* d_out, int out_size, void* d_ws, size_t ws_size,
                              hipStream_t stream) {
  (void)in_sizes; (void)n_in; (void)ws_size;
  const float* x  = (const float*)d_in[0];
  const float* Wg = (const float*)d_in[1];
  const float* bg = (const float*)d_in[2];
  const float* W1 = (const float*)d_in[3];
  const float* b1 = (const float*)d_in[4];
  const float* W2 = (const float*)d_in[5];
  const float* b2 = (const float*)d_in[6];
  float* out = (float*)d_out;

  char* ws = (char*)d_ws;
  int* cnts = (int*)ws;                                      // 256 B (8 used)
  int* list = (int*)(ws + 256);                              // 8*16384*4 = 512 KB
  unsigned short* w1p = (unsigned short*)(ws + 256 + 524288);            // 2 MB
  unsigned short* w2p = (unsigned short*)(ws + 256 + 524288 + 2097152);  // 2 MB

  hipMemsetAsync(cnts, 0, 256, stream);
  hipMemsetAsync(d_out, 0, (size_t)out_size * sizeof(float), stream);

  // prep: blocks [0,512) pack W1, [512,1024) pack W2, [1024,1280) gate.
  // W1 is [E][D][H] = [e][k][n] (K=256,N=512); W2 is [E][H][D] (K=512,N=256).
  hipLaunchKernelGGL(prep_kernel, dim3(1280), dim3(256), 0, stream,
                     W1, W2, w1p, w2p, x, Wg, bg, cnts, list);
  hipLaunchKernelGGL(ffn_kernel, dim3(NE * 512), dim3(256), 0, stream,
                     x, w1p, b1, w2p, b2, cnts, list, out);
}